// Round 5
// baseline (531.857 us; speedup 1.0000x reference)
//
#include <hip/hip_runtime.h>
#include <hip/hip_bf16.h>
#include <hip/hip_cooperative_groups.h>
#include <math.h>

namespace cg = cooperative_groups;

namespace {
constexpr int V = 50000, E = 256, H = 512, S = 500, B = 64, OOVN = 50;
constexpr int VEXT = V + OOVN;   // 50050
constexpr int CCAT = E + 3 * H;  // 1792  (embed | h_new | context)
constexpr int G3 = 3 * H;        // 1536
constexpr int NLB = 391;         // logits tiles / 8 (3128 waves, 3125 active)
constexpr int SMEM_BYTES = 69632;

typedef __attribute__((ext_vector_type(8))) short short8;
typedef __attribute__((ext_vector_type(4))) float f32x4;

struct P {
  const int* tok; const float* ench; const float* pk; const float* prevh;
  const int* extv; const float* emb; const float* Wq; const float* We;
  const float* Wih; const float* Whh; const float* bih; const float* bhh;
  const float* linW; const float* linb; const float* pgW; const float* pgb;
  const float* outW; const float* outb;
  float* out; float* qpart; float* scores; float* alphasT; float* ctxp;
  float* cc; float* gip; float* ghp; float* linpart; float* pgsum;
  float* logits; float* pm; float* pl; float* hout;
  short* cch; short* ccl; short* hh; short* hl; short* lh;
};

__device__ __forceinline__ float wsum(float v) {
#pragma unroll
  for (int off = 32; off > 0; off >>= 1) v += __shfl_xor(v, off, 64);
  return v;
}
__device__ __forceinline__ float sigmoidf(float x) { return 1.f / (1.f + __expf(-x)); }
__device__ __forceinline__ float fast_tanh(float x) {
  x = fminf(fmaxf(x, -15.f), 15.f);
  float e = __expf(2.f * x);
  return __fdividef(e - 1.f, e + 1.f);
}
__device__ __forceinline__ void smerge_s(float& m, float& l, float om, float ol) {
  float nm = fmaxf(m, om);
  if (nm == -INFINITY) { m = nm; return; }
  l = l * __expf(m - nm) + ol * __expf(om - nm);
  m = nm;
}
__device__ __forceinline__ short bf16_rn_s(float f) {
  __hip_bfloat16 h = __float2bfloat16(f);
  return __builtin_bit_cast(short, h);
}
__device__ __forceinline__ void hilo1(float f, short* hi, short* lo) {
  unsigned u = __float_as_uint(f);
  *hi = (short)(u >> 16);
  *lo = bf16_rn_s(f - __uint_as_float(u & 0xffff0000u));
}
__device__ __forceinline__ void hilo8(float4 a, float4 b, short8& hi, short8& lo) {
  float f[8] = {a.x, a.y, a.z, a.w, b.x, b.y, b.z, b.w};
#pragma unroll
  for (int i = 0; i < 8; ++i) {
    unsigned u = __float_as_uint(f[i]);
    hi[i] = (short)(u >> 16);
    lo[i] = bf16_rn_s(f[i] - __uint_as_float(u & 0xffff0000u));
  }
}

// ---- MFMA core (hi/lo accurate): wave computes C[0:64][n0:n0+16] over a K-chunk ----
template <int KSTEPS>
__device__ __forceinline__ void gemm_core(const short* __restrict__ Xhi,
                                          const short* __restrict__ Xlo, int ldx, int xk0,
                                          const float* __restrict__ W, int ldw, int wk0,
                                          int n0, f32x4 acc[4]) {
  const int l = threadIdx.x & 63;
  const int r16 = l & 15, q16 = l >> 4;
#pragma unroll
  for (int t = 0; t < 4; ++t) acc[t] = (f32x4){0.f, 0.f, 0.f, 0.f};
  const float* wp = W + (size_t)(n0 + r16) * ldw + wk0 + q16 * 8;
  const short* xh[4];
  const short* xl[4];
#pragma unroll
  for (int t = 0; t < 4; ++t) {
    int row = t * 16 + r16;
    xh[t] = Xhi + (size_t)row * ldx + xk0 + q16 * 8;
    xl[t] = Xlo + (size_t)row * ldx + xk0 + q16 * 8;
  }
#pragma unroll
  for (int ks = 0; ks < KSTEPS; ++ks) {
    const int ko = ks * 32;
    float4 w0 = *reinterpret_cast<const float4*>(wp + ko);
    float4 w1 = *reinterpret_cast<const float4*>(wp + ko + 4);
    short8 whi, wlo;
    hilo8(w0, w1, whi, wlo);
#pragma unroll
    for (int t = 0; t < 4; ++t) {
      short8 ah = *reinterpret_cast<const short8*>(xh[t] + ko);
      short8 al = *reinterpret_cast<const short8*>(xl[t] + ko);
      acc[t] = __builtin_amdgcn_mfma_f32_16x16x32_bf16(ah, whi, acc[t], 0, 0, 0);
      acc[t] = __builtin_amdgcn_mfma_f32_16x16x32_bf16(al, whi, acc[t], 0, 0, 0);
      acc[t] = __builtin_amdgcn_mfma_f32_16x16x32_bf16(ah, wlo, acc[t], 0, 0, 0);
    }
  }
}
template <int KSTEPS>
__device__ __forceinline__ void gemm_store(const short* Xhi, const short* Xlo, int ldx,
                                           int xk0, const float* W, int ldw, int wk0,
                                           int n0, float* C, int ldc) {
  f32x4 acc[4];
  gemm_core<KSTEPS>(Xhi, Xlo, ldx, xk0, W, ldw, wk0, n0, acc);
  const int l = threadIdx.x & 63;
  const int r16 = l & 15, q16 = l >> 4;
#pragma unroll
  for (int t = 0; t < 4; ++t)
#pragma unroll
    for (int r = 0; r < 4; ++r) {
      int row = t * 16 + q16 * 4 + r;
      C[(size_t)row * ldc + n0 + r16] = acc[t][r];
    }
}

// ================= phases (grid-stride; blockDim == 512) =================

__device__ void ph_prep(const P& p) {
  for (int i = blockIdx.x * blockDim.x + threadIdx.x; i < B * H;
       i += gridDim.x * blockDim.x) {
    hilo1(p.prevh[i], &p.hh[i], &p.hl[i]);
    if (i < B * E) {
      int b = i >> 8, e = i & 255;
      float v = p.emb[(size_t)p.tok[b] * E + e];
      p.cc[b * CCAT + e] = v;
      hilo1(v, &p.cch[b * CCAT + e], &p.ccl[b * CCAT + e]);
    }
  }
}

__device__ void ph_qgh(const P& p) {
  int W = gridDim.x * (blockDim.x >> 6);
  for (int w = blockIdx.x * (blockDim.x >> 6) + (threadIdx.x >> 6); w < 320; w += W) {
    if (w < 128) {
      int c = w >> 5, nt = w & 31;
      gemm_store<4>(p.hh, p.hl, H, c * 128, p.Wq, H, c * 128, nt * 16,
                    p.qpart + (size_t)c * 64 * H, H);
    } else {
      int w2 = w - 128;
      int c = w2 / 96, nt = w2 % 96;
      gemm_store<8>(p.hh, p.hl, H, c * 256, p.Whh, H, c * 256, nt * 16,
                    p.ghp + (size_t)c * 64 * G3, G3);
    }
  }
}

__device__ void ph_scores(const P& p) {
  int lane = threadIdx.x & 63;
  int W = gridDim.x * (blockDim.x >> 6);
  for (int gw = blockIdx.x * (blockDim.x >> 6) + (threadIdx.x >> 6); gw < S * B; gw += W) {
    int s = gw >> 6, b = gw & 63;
    const float* q0 = p.qpart + b * H + lane * 8;
    const float* kr = p.pk + ((size_t)s * B + b) * H + lane * 8;
    const float* er = p.We + lane * 8;
    float part = 0.f;
#pragma unroll
    for (int i = 0; i < 2; ++i) {
      float4 qa = *reinterpret_cast<const float4*>(q0 + i * 4);
      float4 qb = *reinterpret_cast<const float4*>(q0 + 64 * H + i * 4);
      float4 qc = *reinterpret_cast<const float4*>(q0 + 128 * H + i * 4);
      float4 qd = *reinterpret_cast<const float4*>(q0 + 192 * H + i * 4);
      float4 kv = *reinterpret_cast<const float4*>(kr + i * 4);
      float4 ev = *reinterpret_cast<const float4*>(er + i * 4);
      part += fast_tanh(qa.x + qb.x + qc.x + qd.x + kv.x) * ev.x +
              fast_tanh(qa.y + qb.y + qc.y + qd.y + kv.y) * ev.y +
              fast_tanh(qa.z + qb.z + qc.z + qd.z + kv.z) * ev.z +
              fast_tanh(qa.w + qb.w + qc.w + qd.w + kv.w) * ev.w;
    }
    part = wsum(part);
    if (lane == 0) p.scores[s * B + b] = part;
  }
}

__device__ void ph_softmax(const P& p, char* smem) {
  float* rm = (float*)smem;
  float* rl = rm + 8;
  int t = threadIdx.x, w = t >> 6, lane = t & 63;
  for (int b = blockIdx.x; b < B; b += gridDim.x) {
    __syncthreads();
    float v = (t < S) ? p.scores[t * B + b] : -INFINITY;
    float m = v;
#pragma unroll
    for (int off = 32; off > 0; off >>= 1) m = fmaxf(m, __shfl_xor(m, off, 64));
    if (lane == 0) rm[w] = m;
    __syncthreads();
    float bm = rm[0];
#pragma unroll
    for (int i = 1; i < 8; ++i) bm = fmaxf(bm, rm[i]);
    float e = (t < S) ? __expf(v - bm) : 0.f;
    float sw = wsum(e);
    if (lane == 0) rl[w] = sw;
    __syncthreads();
    float tot = rl[0];
#pragma unroll
    for (int i = 1; i < 8; ++i) tot += rl[i];
    if (t < S) p.alphasT[b * S + t] = e / tot;
  }
}

__device__ void ph_ctx(const P& p, char* smem) {
  float* sa = (float*)smem;  // 125 floats
  int t = threadIdx.x;
  for (int it = blockIdx.x; it < 512; it += gridDim.x) {
    int b = it >> 3, chf = (it >> 2) & 1, sh = it & 3;
    __syncthreads();
    if (t < 125) sa[t] = p.alphasT[b * S + sh * 125 + t];
    __syncthreads();
    const float* base = p.ench + ((size_t)(sh * 125) * B + b) * 1024 + chf * 512 + t;
    float a0 = 0.f, a1 = 0.f;
#pragma unroll 5
    for (int s = 0; s < 124; s += 2) {
      a0 += sa[s] * base[(size_t)s * (B * 1024)];
      a1 += sa[s + 1] * base[(size_t)(s + 1) * (B * 1024)];
    }
    a0 += sa[124] * base[(size_t)124 * (B * 1024)];
    p.ctxp[((sh * B + b) * 1024) + chf * 512 + t] = a0 + a1;
  }
}

__device__ void ph_ctx2(const P& p) {
  for (int i = blockIdx.x * blockDim.x + threadIdx.x; i < B * 1024;
       i += gridDim.x * blockDim.x) {
    int b = i >> 10, col = i & 1023;
    float v = p.ctxp[(b)*1024 + col] + p.ctxp[(B + b) * 1024 + col] +
              p.ctxp[(2 * B + b) * 1024 + col] + p.ctxp[(3 * B + b) * 1024 + col];
    int cix = b * CCAT + 768 + col;
    p.cc[cix] = v;
    hilo1(v, &p.cch[cix], &p.ccl[cix]);
  }
}

__device__ void ph_big(const P& p) {
  int W = gridDim.x * (blockDim.x >> 6);
  for (int w = blockIdx.x * (blockDim.x >> 6) + (threadIdx.x >> 6); w < 640; w += W) {
    if (w < 480) {
      int c = w / 96, nt = w % 96;
      int xk0 = (c == 0) ? 0 : 768 + (c - 1) * 256;
      gemm_store<8>(p.cch, p.ccl, CCAT, xk0, p.Wih, 1280, c * 256, nt * 16,
                    p.gip + (size_t)c * 64 * G3, G3);
    } else {
      int w2 = w - 480;
      int c = w2 >> 5, nt = w2 & 31;
      int k0 = (c == 0) ? 0 : 768 + (c - 1) * 256;
      gemm_store<8>(p.cch, p.ccl, CCAT, k0, p.linW, CCAT, k0, nt * 16,
                    p.linpart + (size_t)c * 64 * H, H);
    }
  }
}

__device__ void ph_gates(const P& p, char* smem) {
  float* sl = (float*)smem;  // 8 floats
  int j = threadIdx.x;
  int w = j >> 6, lane = j & 63;
  for (int b = blockIdx.x; b < B; b += gridDim.x) {
    __syncthreads();
    float ir = p.bih[j], iz = p.bih[512 + j], in_ = p.bih[1024 + j];
#pragma unroll
    for (int c = 0; c < 5; ++c) {
      const float* g = p.gip + (size_t)c * 64 * G3 + b * G3;
      ir += g[j]; iz += g[512 + j]; in_ += g[1024 + j];
    }
    float hr = p.bhh[j], hz = p.bhh[512 + j], hn = p.bhh[1024 + j];
#pragma unroll
    for (int c = 0; c < 2; ++c) {
      const float* g = p.ghp + (size_t)c * 64 * G3 + b * G3;
      hr += g[j]; hz += g[512 + j]; hn += g[1024 + j];
    }
    float r = sigmoidf(ir + hr);
    float z = sigmoidf(iz + hz);
    float n = fast_tanh(in_ + r * hn);
    float h = p.prevh[b * H + j];
    float hnew = (1.f - z) * n + z * h;
    p.hout[b * H + j] = hnew;
    p.cc[b * CCAT + E + j] = hnew;
    hilo1(hnew, &p.cch[b * CCAT + E + j], &p.ccl[b * CCAT + E + j]);
    float acc = hnew * p.pgW[E + j];
    acc += p.cc[b * CCAT + 768 + j] * p.pgW[768 + j];
    acc += p.cc[b * CCAT + 1280 + j] * p.pgW[1280 + j];
    if (j < 256) acc += p.cc[b * CCAT + j] * p.pgW[j];
    acc = wsum(acc);
    if (lane == 0) sl[w] = acc;
    __syncthreads();
    if (j == 0) {
      float tot = p.pgb[0];
#pragma unroll
      for (int i = 0; i < 8; ++i) tot += sl[i];
      p.pgsum[b] = tot;
    }
  }
}

// lin h-part GEMM + partial-sum + bias -> lh (bf16)
__device__ void ph_linfin(const P& p) {
  int W = gridDim.x * (blockDim.x >> 6);
  for (int w = blockIdx.x * (blockDim.x >> 6) + (threadIdx.x >> 6); w < 32; w += W) {
    f32x4 acc[4];
    gemm_core<16>(p.cch, p.ccl, CCAT, 256, p.linW, CCAT, 256, w * 16, acc);
    const int l = threadIdx.x & 63;
    const int r16 = l & 15, q16 = l >> 4;
    int col = w * 16 + r16;
    float bv = p.linb[col];
#pragma unroll
    for (int t = 0; t < 4; ++t)
#pragma unroll
      for (int r = 0; r < 4; ++r) {
        int row = t * 16 + q16 * 4 + r;
        float v = acc[t][r] + bv;
#pragma unroll
        for (int c = 0; c < 5; ++c) v += p.linpart[(size_t)c * 64 * H + row * H + col];
        p.lh[row * H + col] = bf16_rn_s(v);
      }
  }
}

__device__ void ph_logits(const P& p, char* smem) {
  char* xb = smem;  // 64 KB staged activations
  float (*pml)[64][2] = (float(*)[64][2])(smem + 65536);
  int tid = threadIdx.x;
  const int l = tid & 63, r16 = l & 15, q16 = l >> 4, wid = tid >> 6;
#pragma unroll
  for (int k = 0; k < 8; ++k) {
    int m = k * 512 + tid;
    int row = m >> 6;
    short8 v = *reinterpret_cast<const short8*>(p.lh + (size_t)m * 8);
    int byte = (m * 16) ^ ((row & 7) << 4);
    *reinterpret_cast<short8*>(xb + byte) = v;
  }
  int arow[4], aswz[4];
#pragma unroll
  for (int t = 0; t < 4; ++t) {
    int row = t * 16 + r16;
    arow[t] = row * 1024 + q16 * 16;
    aswz[t] = (row & 7) << 4;
  }
  __syncthreads();
  for (int vb = blockIdx.x; vb < NLB; vb += gridDim.x) {
    int tile = vb * 8 + wid;
    if (tile < V / 16) {
      const int n0 = tile * 16;
      f32x4 acc[4];
#pragma unroll
      for (int t = 0; t < 4; ++t) acc[t] = (f32x4){0.f, 0.f, 0.f, 0.f};
      const float* wp = p.outW + (size_t)(n0 + r16) * H + q16 * 8;
#pragma unroll
      for (int ks = 0; ks < 16; ++ks) {
        float4 w0 = *reinterpret_cast<const float4*>(wp + ks * 32);
        float4 w1 = *reinterpret_cast<const float4*>(wp + ks * 32 + 4);
        short8 wh;
        wh[0] = bf16_rn_s(w0.x); wh[1] = bf16_rn_s(w0.y);
        wh[2] = bf16_rn_s(w0.z); wh[3] = bf16_rn_s(w0.w);
        wh[4] = bf16_rn_s(w1.x); wh[5] = bf16_rn_s(w1.y);
        wh[6] = bf16_rn_s(w1.z); wh[7] = bf16_rn_s(w1.w);
#pragma unroll
        for (int t = 0; t < 4; ++t) {
          short8 a = *reinterpret_cast<const short8*>(xb + ((arow[t] + ks * 64) ^ aswz[t]));
          acc[t] = __builtin_amdgcn_mfma_f32_16x16x32_bf16(a, wh, acc[t], 0, 0, 0);
        }
      }
      float bv = p.outb[n0 + r16];
#pragma unroll
      for (int t = 0; t < 4; ++t)
#pragma unroll
        for (int r = 0; r < 4; ++r) {
          float y = acc[t][r] + bv;
          int row = t * 16 + q16 * 4 + r;
          p.logits[(size_t)row * V + n0 + r16] = y;
          float m = y;
#pragma unroll
          for (int off = 8; off > 0; off >>= 1) m = fmaxf(m, __shfl_xor(m, off, 64));
          float e = __expf(y - m);
#pragma unroll
          for (int off = 8; off > 0; off >>= 1) e += __shfl_xor(e, off, 64);
          if (r16 == 0) { pml[wid][row][0] = m; pml[wid][row][1] = e; }
        }
    } else if (r16 == 0) {
#pragma unroll
      for (int t = 0; t < 4; ++t)
#pragma unroll
        for (int r = 0; r < 4; ++r) {
          int row = t * 16 + q16 * 4 + r;
          pml[wid][row][0] = -INFINITY;
          pml[wid][row][1] = 0.f;
        }
    }
    __syncthreads();
    if (tid < 64) {
      float m = pml[0][tid][0], lv = pml[0][tid][1];
#pragma unroll
      for (int i = 1; i < 8; ++i) smerge_s(m, lv, pml[i][tid][0], pml[i][tid][1]);
      p.pm[vb * 64 + tid] = m;
      p.pl[vb * 64 + tid] = lv;
    }
    __syncthreads();
  }
}

__device__ void ph_final(const P& p, char* smem) {
  float* sp_ = (float*)smem;            // 5056 floats
  float* rr = (float*)(smem + 20224);   // 8
  float* rl2 = rr + 8;                  // 8
  int t = threadIdx.x, w = t >> 6, lane = t & 63;
  for (int it = blockIdx.x; it < 640; it += gridDim.x) {
    int b = it & 63, c = it >> 6;
    float m = -INFINITY, lv = 0.f;
    if (t < NLB) { m = p.pm[t * 64 + b]; lv = p.pl[t * 64 + b]; }
#pragma unroll
    for (int off = 32; off > 0; off >>= 1) {
      float om = __shfl_xor(m, off, 64), ol = __shfl_xor(lv, off, 64);
      smerge_s(m, lv, om, ol);
    }
    if (lane == 0) { rr[w] = m; rl2[w] = lv; }
    __syncthreads();
    m = rr[0]; lv = rl2[0];
#pragma unroll
    for (int i = 1; i < 8; ++i) smerge_s(m, lv, rr[i], rl2[i]);
    float pg = sigmoidf(p.pgsum[b]);
    float scale = pg / lv;
    const int base = c * 5000;
    const int len = (c == 9) ? 5050 : 5000;
    const float* lr = p.logits + (size_t)b * V + base;
    for (int i = t; i < len; i += 512)
      sp_[i] = (i < 5000) ? scale * __expf(lr[i] - m) + 1e-12f : 1e-12f;
    __syncthreads();
    float wgt = 1.f - pg;
    for (int s = t; s < S; s += 512) {
      int idx = p.extv[b * S + s] - base;
      if ((unsigned)idx < (unsigned)len) atomicAdd(&sp_[idx], wgt * p.alphasT[b * S + s]);
    }
    __syncthreads();
    float* orow = p.out + (size_t)b * VEXT + base;
    for (int i = t; i < len; i += 512) orow[i] = __logf(sp_[i]);
    __syncthreads();
  }
}

// ================= mega (cooperative) =================
__global__ void __launch_bounds__(512, 4) k_mega(P p) {
  __shared__ __align__(16) char smem[SMEM_BYTES];
  cg::grid_group g = cg::this_grid();
  ph_prep(p);          g.sync();
  ph_qgh(p);           g.sync();
  ph_scores(p);        g.sync();
  ph_softmax(p, smem); g.sync();
  ph_ctx(p, smem);     g.sync();
  ph_ctx2(p);          g.sync();
  ph_big(p);           g.sync();
  ph_gates(p, smem);   g.sync();
  ph_linfin(p);        g.sync();
  ph_logits(p, smem);  g.sync();
  ph_final(p, smem);
}

// ================= fallback wrappers =================
__global__ void __launch_bounds__(512) k_p0(P p) { ph_prep(p); }
__global__ void __launch_bounds__(512) k_p1(P p) { ph_qgh(p); }
__global__ void __launch_bounds__(512) k_p2(P p) { ph_scores(p); }
__global__ void __launch_bounds__(512) k_p3(P p) {
  __shared__ __align__(16) char smem[64];
  ph_softmax(p, smem);
}
__global__ void __launch_bounds__(512) k_p4(P p) {
  __shared__ __align__(16) char smem[512];
  ph_ctx(p, smem);
}
__global__ void __launch_bounds__(512) k_p5(P p) { ph_ctx2(p); }
__global__ void __launch_bounds__(512) k_p6(P p) { ph_big(p); }
__global__ void __launch_bounds__(512) k_p7(P p) {
  __shared__ __align__(16) char smem[64];
  ph_gates(p, smem);
}
__global__ void __launch_bounds__(512) k_p8(P p) { ph_linfin(p); }
__global__ void __launch_bounds__(512) k_p9(P p) {
  __shared__ __align__(16) char smem[SMEM_BYTES];
  ph_logits(p, smem);
}
__global__ void __launch_bounds__(512) k_p10(P p) {
  __shared__ __align__(16) char smem[20304];
  ph_final(p, smem);
}
}  // namespace

extern "C" void kernel_launch(void* const* d_in, const int* in_sizes, int n_in,
                              void* d_out, int out_size, void* d_ws, size_t ws_size,
                              hipStream_t stream) {
  P p;
  p.tok   = (const int*)d_in[0];
  p.ench  = (const float*)d_in[1];
  p.pk    = (const float*)d_in[2];
  p.prevh = (const float*)d_in[4];
  p.extv  = (const int*)d_in[5];
  p.emb   = (const float*)d_in[7];
  p.Wq    = (const float*)d_in[8];
  p.We    = (const float*)d_in[9];
  p.Wih   = (const float*)d_in[10];
  p.Whh   = (const float*)d_in[11];
  p.bih   = (const float*)d_in[12];
  p.bhh   = (const float*)d_in[13];
  p.linW  = (const float*)d_in[14];
  p.linb  = (const float*)d_in[15];
  p.pgW   = (const float*)d_in[16];
  p.pgb   = (const float*)d_in[17];
  p.outW  = (const float*)d_in[18];
  p.outb  = (const float*)d_in[19];
  p.out   = (float*)d_out;

  float* ws = (float*)d_ws;
  p.qpart   = ws;                    // 4*64*512   = 131072
  p.scores  = p.qpart + 131072;      // 32000
  p.alphasT = p.scores + 32000;      // 32000
  p.ctxp    = p.alphasT + 32000;     // 4*64*1024  = 262144
  p.cc      = p.ctxp + 262144;       // 64*1792    = 114688
  p.gip     = p.cc + 114688;         // 5*64*1536  = 491520
  p.ghp     = p.gip + 491520;        // 2*64*1536  = 196608
  p.linpart = p.ghp + 196608;        // 5*64*512   = 163840
  p.pgsum   = p.linpart + 163840;    // 64
  p.logits  = p.pgsum + 64;          // 64*50000   = 3200000
  p.pm      = p.logits + 3200000;    // 25024
  p.pl      = p.pm + 25024;          // 25024
  short* sp = (short*)(p.pl + 25024);
  p.cch = sp;                        // 114688
  p.ccl = p.cch + 114688;            // 114688
  p.hh  = p.ccl + 114688;            // 32768
  p.hl  = p.hh + 32768;              // 32768
  p.lh  = p.hl + 32768;              // 32768
  p.hout = p.out + (size_t)B * VEXT;

  bool launched = false;
  int occ = 0;
  hipError_t oe =
      hipOccupancyMaxActiveBlocksPerMultiprocessor(&occ, (const void*)k_mega, 512, 0);
  if (oe == hipSuccess && occ > 0) {
    int devId = 0;
    hipGetDevice(&devId);
    hipDeviceProp_t prop;
    if (hipGetDeviceProperties(&prop, devId) == hipSuccess) {
      int nb = occ * prop.multiProcessorCount;
      if (nb > 512) nb = 512;
      if (nb >= 64) {
        void* args[] = {(void*)&p};
        hipError_t rc = hipLaunchCooperativeKernel((const void*)k_mega, dim3(nb),
                                                   dim3(512), args, 0, stream);
        launched = (rc == hipSuccess);
      }
    }
  }
  if (!launched) {
    k_p0<<<dim3(64), dim3(512), 0, stream>>>(p);
    k_p1<<<dim3(40), dim3(512), 0, stream>>>(p);
    k_p2<<<dim3(4000), dim3(512), 0, stream>>>(p);
    k_p3<<<dim3(64), dim3(512), 0, stream>>>(p);
    k_p4<<<dim3(512), dim3(512), 0, stream>>>(p);
    k_p5<<<dim3(128), dim3(512), 0, stream>>>(p);
    k_p6<<<dim3(80), dim3(512), 0, stream>>>(p);
    k_p7<<<dim3(64), dim3(512), 0, stream>>>(p);
    k_p8<<<dim3(4), dim3(512), 0, stream>>>(p);
    k_p9<<<dim3(391), dim3(512), 0, stream>>>(p);
    k_p10<<<dim3(640), dim3(512), 0, stream>>>(p);
  }
}

// Round 6
// 149.948 us; speedup vs baseline: 3.5469x; 3.5469x over previous
//
#include <hip/hip_runtime.h>
#include <hip/hip_bf16.h>
#include <math.h>

namespace {
constexpr int V = 50000, E = 256, H = 512, S = 500, B = 64, OOVN = 50;
constexpr int VEXT = V + OOVN;   // 50050
constexpr int CCAT = E + 3 * H;  // 1792  (embed | h_new | context)
constexpr int G3 = 3 * H;        // 1536
constexpr int NLB = 391;         // logits blocks (3128 waves, 3125 active)

typedef __attribute__((ext_vector_type(8))) short short8;
typedef __attribute__((ext_vector_type(4))) float f32x4;

__device__ __forceinline__ float wsum(float v) {
#pragma unroll
  for (int off = 32; off > 0; off >>= 1) v += __shfl_xor(v, off, 64);
  return v;
}
__device__ __forceinline__ float sigmoidf(float x) { return 1.f / (1.f + __expf(-x)); }
__device__ __forceinline__ float fast_tanh(float x) {
  x = fminf(fmaxf(x, -15.f), 15.f);
  float e = __expf(2.f * x);
  return __fdividef(e - 1.f, e + 1.f);
}
__device__ __forceinline__ void smerge_s(float& m, float& l, float om, float ol) {
  float nm = fmaxf(m, om);
  if (nm == -INFINITY) { m = nm; return; }
  l = l * __expf(m - nm) + ol * __expf(om - nm);
  m = nm;
}
__device__ __forceinline__ short bf16_rn_s(float f) {
  __hip_bfloat16 h = __float2bfloat16(f);
  return __builtin_bit_cast(short, h);
}
__device__ __forceinline__ void hilo8(float4 a, float4 b, short8& hi, short8& lo) {
  float f[8] = {a.x, a.y, a.z, a.w, b.x, b.y, b.z, b.w};
#pragma unroll
  for (int i = 0; i < 8; ++i) {
    unsigned u = __float_as_uint(f[i]);
    hi[i] = (short)(u >> 16);
    lo[i] = bf16_rn_s(f[i] - __uint_as_float(u & 0xffff0000u));
  }
}

// ---- MFMA core, fp32 X with in-register hi/lo split; wave does C[0:64][n0:n0+16] ----
template <int KSTEPS>
__device__ __forceinline__ void gemm_core_f32(const float* __restrict__ X, int ldx,
                                              int xk0, const float* __restrict__ W,
                                              int ldw, int wk0, int n0, f32x4 acc[4]) {
  const int l = threadIdx.x & 63;
  const int r16 = l & 15, q16 = l >> 4;
#pragma unroll
  for (int t = 0; t < 4; ++t) acc[t] = (f32x4){0.f, 0.f, 0.f, 0.f};
  const float* wp = W + (size_t)(n0 + r16) * ldw + wk0 + q16 * 8;
  const float* xp[4];
#pragma unroll
  for (int t = 0; t < 4; ++t) xp[t] = X + (size_t)(t * 16 + r16) * ldx + xk0 + q16 * 8;
#pragma unroll
  for (int ks = 0; ks < KSTEPS; ++ks) {
    const int ko = ks * 32;
    float4 w0 = *reinterpret_cast<const float4*>(wp + ko);
    float4 w1 = *reinterpret_cast<const float4*>(wp + ko + 4);
    short8 whi, wlo;
    hilo8(w0, w1, whi, wlo);
#pragma unroll
    for (int t = 0; t < 4; ++t) {
      float4 x0 = *reinterpret_cast<const float4*>(xp[t] + ko);
      float4 x1 = *reinterpret_cast<const float4*>(xp[t] + ko + 4);
      short8 ah, al;
      hilo8(x0, x1, ah, al);
      acc[t] = __builtin_amdgcn_mfma_f32_16x16x32_bf16(ah, whi, acc[t], 0, 0, 0);
      acc[t] = __builtin_amdgcn_mfma_f32_16x16x32_bf16(al, whi, acc[t], 0, 0, 0);
      acc[t] = __builtin_amdgcn_mfma_f32_16x16x32_bf16(ah, wlo, acc[t], 0, 0, 0);
    }
  }
}
template <int KSTEPS>
__device__ __forceinline__ void gemm_store_f32(const float* X, int ldx, int xk0,
                                               const float* W, int ldw, int wk0, int n0,
                                               float* C, int ldc) {
  f32x4 acc[4];
  gemm_core_f32<KSTEPS>(X, ldx, xk0, W, ldw, wk0, n0, acc);
  const int l = threadIdx.x & 63;
  const int r16 = l & 15, q16 = l >> 4;
#pragma unroll
  for (int t = 0; t < 4; ++t)
#pragma unroll
    for (int r = 0; r < 4; ++r) {
      int row = t * 16 + q16 * 4 + r;
      C[(size_t)row * ldc + n0 + r16] = acc[t][r];
    }
}

// ---- head: q gemm (4 K-chunks) + gh gemm (2 K-chunks) + embed gather + cc-ctx zero ----
__global__ void __launch_bounds__(256) k_head(const float* __restrict__ prevh,
                                              const float* __restrict__ Wq,
                                              const float* __restrict__ Whh,
                                              const int* __restrict__ tok,
                                              const float* __restrict__ emb,
                                              float* __restrict__ qpart,
                                              float* __restrict__ ghp,
                                              float* __restrict__ cc) {
  int gw = blockIdx.x * 4 + (threadIdx.x >> 6);  // 0..335
  if (gw < 128) {
    int c = gw >> 5, nt = gw & 31;
    gemm_store_f32<4>(prevh, H, c * 128, Wq, H, c * 128, nt * 16,
                      qpart + (size_t)c * 64 * H, H);
  } else if (gw < 320) {
    int w2 = gw - 128;
    int c = w2 / 96, nt = w2 % 96;
    gemm_store_f32<8>(prevh, H, c * 256, Whh, H, c * 256, nt * 16,
                      ghp + (size_t)c * 64 * G3, G3);
  } else {
    int idx = (gw - 320) * 64 + (threadIdx.x & 63);  // 0..1023
    for (int i = idx; i < B * E; i += 1024) {
      int b = i >> 8, e = i & 255;
      cc[b * CCAT + e] = emb[(size_t)tok[b] * E + e];
    }
    for (int i = idx; i < B * 1024; i += 1024) {
      int b = i >> 10, col = i & 1023;
      cc[b * CCAT + 768 + col] = 0.f;
    }
  }
}

// ---- scoresT[b][s] = sum_h tanh(q+pk)*We ; wave per (s,b) ----
__global__ void k_scores(const float* __restrict__ qpart, const float* __restrict__ pk,
                         const float* __restrict__ We, float* __restrict__ scoresT) {
  int lane = threadIdx.x & 63;
  int gw = blockIdx.x * 4 + (threadIdx.x >> 6);  // 0..31999
  int s = gw >> 6, b = gw & 63;
  const float* q0 = qpart + b * H + lane * 8;
  const float* kr = pk + ((size_t)s * B + b) * H + lane * 8;
  const float* er = We + lane * 8;
  float part = 0.f;
#pragma unroll
  for (int i = 0; i < 2; ++i) {
    float4 qa = *reinterpret_cast<const float4*>(q0 + i * 4);
    float4 qb = *reinterpret_cast<const float4*>(q0 + 64 * H + i * 4);
    float4 qc = *reinterpret_cast<const float4*>(q0 + 128 * H + i * 4);
    float4 qd = *reinterpret_cast<const float4*>(q0 + 192 * H + i * 4);
    float4 kv = *reinterpret_cast<const float4*>(kr + i * 4);
    float4 ev = *reinterpret_cast<const float4*>(er + i * 4);
    part += fast_tanh(qa.x + qb.x + qc.x + qd.x + kv.x) * ev.x +
            fast_tanh(qa.y + qb.y + qc.y + qd.y + kv.y) * ev.y +
            fast_tanh(qa.z + qb.z + qc.z + qd.z + kv.z) * ev.z +
            fast_tanh(qa.w + qb.w + qc.w + qd.w + kv.w) * ev.w;
  }
  part = wsum(part);
  if (lane == 0) scoresT[b * S + s] = part;
}

// ---- column softmax over s -> alphasT[B][S] ----
__global__ void k_softmax_s(const float* __restrict__ scoresT, float* __restrict__ alphasT) {
  int b = blockIdx.x, t = threadIdx.x;  // 512 threads
  int w = t >> 6, lane = t & 63;
  __shared__ float rm[8], rl[8];
  float v = (t < S) ? scoresT[b * S + t] : -INFINITY;
  float m = v;
#pragma unroll
  for (int off = 32; off > 0; off >>= 1) m = fmaxf(m, __shfl_xor(m, off, 64));
  if (lane == 0) rm[w] = m;
  __syncthreads();
  float bm = rm[0];
#pragma unroll
  for (int i = 1; i < 8; ++i) bm = fmaxf(bm, rm[i]);
  float e = (t < S) ? __expf(v - bm) : 0.f;
  float sw = wsum(e);
  if (lane == 0) rl[w] = sw;
  __syncthreads();
  float tot = rl[0];
#pragma unroll
  for (int i = 1; i < 8; ++i) tot += rl[i];
  if (t < S) alphasT[b * S + t] = e / tot;
}

// ---- context: cc[b][768+col] += sum_{s in half} alphas*ench (2-way commutative atomics) ----
__global__ void k_ctx(const float* __restrict__ alphasT, const float* __restrict__ ench,
                      float* __restrict__ cc) {
  int x = blockIdx.x;  // 512 = 64b * 4qd * 2sh
  int b = x >> 3, qd = (x >> 2) & 1 * 0 + ((x & 7) >> 1), sh = x & 1;
  int t = threadIdx.x;  // 256
  __shared__ float sa[250];
  if (t < 250) sa[t] = alphasT[b * S + sh * 250 + t];
  __syncthreads();
  const float* base = ench + ((size_t)(sh * 250) * B + b) * 1024 + qd * 256 + t;
  float a0 = 0.f, a1 = 0.f, a2 = 0.f, a3 = 0.f;
#pragma unroll 4
  for (int s = 0; s < 248; s += 4) {
    a0 += sa[s] * base[(size_t)s * (B * 1024)];
    a1 += sa[s + 1] * base[(size_t)(s + 1) * (B * 1024)];
    a2 += sa[s + 2] * base[(size_t)(s + 2) * (B * 1024)];
    a3 += sa[s + 3] * base[(size_t)(s + 3) * (B * 1024)];
  }
  a0 += sa[248] * base[(size_t)248 * (B * 1024)];
  a1 += sa[249] * base[(size_t)249 * (B * 1024)];
  atomicAdd(&cc[b * CCAT + 768 + qd * 256 + t], (a0 + a1) + (a2 + a3));
}

// ---- big fused gemm: gi (5 chunks) + lin embed/ctx chunks (5) ----
__global__ void __launch_bounds__(256) k_gemm_big(const float* __restrict__ cc,
                                                  const float* __restrict__ Wih,
                                                  const float* __restrict__ linW,
                                                  float* __restrict__ gip,
                                                  float* __restrict__ linpart) {
  int w = blockIdx.x * 4 + (threadIdx.x >> 6);  // 0..639
  if (w < 480) {
    int c = w / 96, nt = w % 96;
    int xk0 = (c == 0) ? 0 : 768 + (c - 1) * 256;
    gemm_store_f32<8>(cc, CCAT, xk0, Wih, 1280, c * 256, nt * 16,
                      gip + (size_t)c * 64 * G3, G3);
  } else {
    int w2 = w - 480;
    int c = w2 >> 5, nt = w2 & 31;
    int k0 = (c == 0) ? 0 : 768 + (c - 1) * 256;
    gemm_store_f32<8>(cc, CCAT, k0, linW, CCAT, k0, nt * 16,
                      linpart + (size_t)c * 64 * H, H);
  }
}

// ---- GRU gates + p_gen: block per b, 512 threads ----
__global__ void k_gates(const float* __restrict__ gip, const float* __restrict__ ghp,
                        const float* __restrict__ bih, const float* __restrict__ bhh,
                        const float* __restrict__ prevh, const float* __restrict__ pgW,
                        const float* __restrict__ pgb, float* __restrict__ cc,
                        float* __restrict__ hout, float* __restrict__ pgsum) {
  int b = blockIdx.x, j = threadIdx.x;  // 64 x 512
  float ir = bih[j], iz = bih[512 + j], in_ = bih[1024 + j];
#pragma unroll
  for (int c = 0; c < 5; ++c) {
    const float* g = gip + (size_t)c * 64 * G3 + b * G3;
    ir += g[j]; iz += g[512 + j]; in_ += g[1024 + j];
  }
  float hr = bhh[j], hz = bhh[512 + j], hn = bhh[1024 + j];
#pragma unroll
  for (int c = 0; c < 2; ++c) {
    const float* g = ghp + (size_t)c * 64 * G3 + b * G3;
    hr += g[j]; hz += g[512 + j]; hn += g[1024 + j];
  }
  float r = sigmoidf(ir + hr);
  float z = sigmoidf(iz + hz);
  float n = fast_tanh(in_ + r * hn);
  float h = prevh[b * H + j];
  float hnew = (1.f - z) * n + z * h;
  hout[b * H + j] = hnew;
  cc[b * CCAT + E + j] = hnew;
  float acc = hnew * pgW[E + j];
  acc += cc[b * CCAT + 768 + j] * pgW[768 + j];
  acc += cc[b * CCAT + 1280 + j] * pgW[1280 + j];
  if (j < 256) acc += cc[b * CCAT + j] * pgW[j];
  acc = wsum(acc);
  __shared__ float sl[8];
  int w = j >> 6, lane = j & 63;
  if (lane == 0) sl[w] = acc;
  __syncthreads();
  if (j == 0) {
    float tot = pgb[0];
#pragma unroll
    for (int i = 0; i < 8; ++i) tot += sl[i];
    pgsum[b] = tot;
  }
}

// ---- lin h-part gemm (K=512) + sum 5 partials + bias -> lh bf16 ----
__global__ void __launch_bounds__(256) k_linfin(const float* __restrict__ cc,
                                                const float* __restrict__ linW,
                                                const float* __restrict__ linpart,
                                                const float* __restrict__ linb,
                                                short* __restrict__ lh) {
  int w = blockIdx.x * 4 + (threadIdx.x >> 6);  // 0..31
  f32x4 acc[4];
  gemm_core_f32<16>(cc, CCAT, 256, linW, CCAT, 256, w * 16, acc);
  const int l = threadIdx.x & 63;
  const int r16 = l & 15, q16 = l >> 4;
  int col = w * 16 + r16;
  float bv = linb[col];
#pragma unroll
  for (int t = 0; t < 4; ++t)
#pragma unroll
    for (int r = 0; r < 4; ++r) {
      int row = t * 16 + q16 * 4 + r;
      float v = acc[t][r] + bv;
#pragma unroll
      for (int c = 0; c < 5; ++c) v += linpart[(size_t)c * 64 * H + row * H + col];
      lh[row * H + col] = bf16_rn_s(v);
    }
}

// ---- logits gemm + per-block online-softmax partials ----
__global__ void __launch_bounds__(512) k_gemm_logits(
    const short* __restrict__ lh, const float* __restrict__ outW,
    const float* __restrict__ outb, float* __restrict__ logits,
    float* __restrict__ pm, float* __restrict__ pl) {
  __shared__ __align__(16) short xs[64 * 512];
  __shared__ float pml[8][64][2];
  char* xb = reinterpret_cast<char*>(xs);
  int tid = threadIdx.x;
#pragma unroll
  for (int k = 0; k < 8; ++k) {
    int m = k * 512 + tid;
    int row = m >> 6;
    short8 v = *reinterpret_cast<const short8*>(lh + (size_t)m * 8);
    int byte = (m * 16) ^ ((row & 7) << 4);
    *reinterpret_cast<short8*>(xb + byte) = v;
  }
  __syncthreads();
  const int l = tid & 63;
  const int r16 = l & 15, q16 = l >> 4;
  const int wid = tid >> 6;
  const int waveId = blockIdx.x * 8 + wid;
  const bool active = waveId < V / 16;
  if (active) {
    const int n0 = waveId * 16;
    f32x4 acc[4];
#pragma unroll
    for (int t = 0; t < 4; ++t) acc[t] = (f32x4){0.f, 0.f, 0.f, 0.f};
    const float* wp = outW + (size_t)(n0 + r16) * H + q16 * 8;
    int arow[4], aswz[4];
#pragma unroll
    for (int t = 0; t < 4; ++t) {
      int row = t * 16 + r16;
      arow[t] = row * 1024 + q16 * 16;
      aswz[t] = (row & 7) << 4;
    }
#pragma unroll
    for (int ks = 0; ks < 16; ++ks) {
      float4 w0 = *reinterpret_cast<const float4*>(wp + ks * 32);
      float4 w1 = *reinterpret_cast<const float4*>(wp + ks * 32 + 4);
      short8 wh;
      wh[0] = bf16_rn_s(w0.x); wh[1] = bf16_rn_s(w0.y);
      wh[2] = bf16_rn_s(w0.z); wh[3] = bf16_rn_s(w0.w);
      wh[4] = bf16_rn_s(w1.x); wh[5] = bf16_rn_s(w1.y);
      wh[6] = bf16_rn_s(w1.z); wh[7] = bf16_rn_s(w1.w);
#pragma unroll
      for (int t = 0; t < 4; ++t) {
        short8 a = *reinterpret_cast<const short8*>(xb + ((arow[t] + ks * 64) ^ aswz[t]));
        acc[t] = __builtin_amdgcn_mfma_f32_16x16x32_bf16(a, wh, acc[t], 0, 0, 0);
      }
    }
    float bv = outb[n0 + r16];
#pragma unroll
    for (int t = 0; t < 4; ++t)
#pragma unroll
      for (int r = 0; r < 4; ++r) {
        float y = acc[t][r] + bv;
        int row = t * 16 + q16 * 4 + r;
        logits[(size_t)row * V + n0 + r16] = y;
        float m = y;
#pragma unroll
        for (int off = 8; off > 0; off >>= 1) m = fmaxf(m, __shfl_xor(m, off, 64));
        float e = __expf(y - m);
#pragma unroll
        for (int off = 8; off > 0; off >>= 1) e += __shfl_xor(e, off, 64);
        if (r16 == 0) { pml[wid][row][0] = m; pml[wid][row][1] = e; }
      }
  } else if (r16 == 0) {
#pragma unroll
    for (int t = 0; t < 4; ++t)
#pragma unroll
      for (int r = 0; r < 4; ++r) {
        int row = t * 16 + q16 * 4 + r;
        pml[wid][row][0] = -INFINITY;
        pml[wid][row][1] = 0.f;
      }
  }
  __syncthreads();
  if (tid < 64) {
    float m = pml[0][tid][0], lv = pml[0][tid][1];
#pragma unroll
    for (int i = 1; i < 8; ++i) smerge_s(m, lv, pml[i][tid][0], pml[i][tid][1]);
    pm[blockIdx.x * 64 + tid] = m;
    pl[blockIdx.x * 64 + tid] = lv;
  }
}

// ---- final: reduce partials -> probs in LDS -> scatter (LDS atomics) -> log -> out ----
__global__ void k_final(const float* __restrict__ logits, const float* __restrict__ pm,
                        const float* __restrict__ pl, const float* __restrict__ pgsum,
                        const int* __restrict__ extv, const float* __restrict__ alphasT,
                        float* __restrict__ out) {
  int b = blockIdx.x, c = blockIdx.y, t = threadIdx.x;  // 64 x 10, 256 thr
  __shared__ float sp_[5056];
  __shared__ float rm[4], rl[4];
  float m = -INFINITY, lv = 0.f;
  for (int i = t; i < NLB; i += 256) smerge_s(m, lv, pm[i * 64 + b], pl[i * 64 + b]);
#pragma unroll
  for (int off = 32; off > 0; off >>= 1) {
    float om = __shfl_xor(m, off, 64), ol = __shfl_xor(lv, off, 64);
    smerge_s(m, lv, om, ol);
  }
  int w = t >> 6, lane = t & 63;
  if (lane == 0) { rm[w] = m; rl[w] = lv; }
  __syncthreads();
  m = rm[0]; lv = rl[0];
#pragma unroll
  for (int i = 1; i < 4; ++i) smerge_s(m, lv, rm[i], rl[i]);
  float pg = sigmoidf(pgsum[b]);
  float scale = pg / lv;
  const int base = c * 5000;
  const int len = (c == 9) ? 5050 : 5000;
  const float* lr = logits + (size_t)b * V + base;
  for (int i = t; i < len; i += 256)
    sp_[i] = (i < 5000) ? scale * __expf(lr[i] - m) + 1e-12f : 1e-12f;
  __syncthreads();
  float wgt = 1.f - pg;
  for (int s = t; s < S; s += 256) {
    int idx = extv[b * S + s] - base;
    if ((unsigned)idx < (unsigned)len) atomicAdd(&sp_[idx], wgt * alphasT[b * S + s]);
  }
  __syncthreads();
  float* orow = out + (size_t)b * VEXT + base;
  for (int i = t; i < len; i += 256) orow[i] = __logf(sp_[i]);
}
}  // namespace

extern "C" void kernel_launch(void* const* d_in, const int* in_sizes, int n_in,
                              void* d_out, int out_size, void* d_ws, size_t ws_size,
                              hipStream_t stream) {
  const int*   tok   = (const int*)d_in[0];
  const float* ench  = (const float*)d_in[1];
  const float* pk    = (const float*)d_in[2];
  const float* prevh = (const float*)d_in[4];
  const int*   extv  = (const int*)d_in[5];
  const float* emb   = (const float*)d_in[7];
  const float* Wq    = (const float*)d_in[8];
  const float* We    = (const float*)d_in[9];
  const float* Wih   = (const float*)d_in[10];
  const float* Whh   = (const float*)d_in[11];
  const float* bih   = (const float*)d_in[12];
  const float* bhh   = (const float*)d_in[13];
  const float* linW  = (const float*)d_in[14];
  const float* linb  = (const float*)d_in[15];
  const float* pgW   = (const float*)d_in[16];
  const float* pgb   = (const float*)d_in[17];
  const float* outW  = (const float*)d_in[18];
  const float* outb  = (const float*)d_in[19];

  float* out = (float*)d_out;
  float* ws = (float*)d_ws;

  float* qpart   = ws;                   // 4*64*512 = 131072
  float* scoresT = qpart + 131072;       // 32000
  float* alphasT = scoresT + 32000;      // 32000
  float* cc      = alphasT + 32000;      // 64*1792 = 114688
  float* gip     = cc + 114688;          // 5*64*1536 = 491520
  float* ghp     = gip + 491520;         // 2*64*1536 = 196608
  float* linpart = ghp + 196608;         // 5*64*512 = 163840
  float* pgsum   = linpart + 163840;     // 64
  float* logits  = pgsum + 64;           // 64*50000 = 3200000
  float* pm      = logits + 3200000;     // 25024
  float* pl      = pm + 25024;           // 25024
  short* lh      = (short*)(pl + 25024); // 32768 shorts
  float* hout    = out + (size_t)B * VEXT;

  k_head<<<dim3(84), dim3(256), 0, stream>>>(prevh, Wq, Whh, tok, emb, qpart, ghp, cc);
  k_scores<<<dim3(8000), dim3(256), 0, stream>>>(qpart, pk, We, scoresT);
  k_softmax_s<<<dim3(B), dim3(512), 0, stream>>>(scoresT, alphasT);
  k_ctx<<<dim3(512), dim3(256), 0, stream>>>(alphasT, ench, cc);
  k_gemm_big<<<dim3(160), dim3(256), 0, stream>>>(cc, Wih, linW, gip, linpart);
  k_gates<<<dim3(B), dim3(512), 0, stream>>>(gip, ghp, bih, bhh, prevh, pgW, pgb, cc,
                                             hout, pgsum);
  k_linfin<<<dim3(8), dim3(256), 0, stream>>>(cc, linW, linpart, linb, lh);
  k_gemm_logits<<<dim3(NLB), dim3(512), 0, stream>>>(lh, outW, outb, logits, pm, pl);
  k_final<<<dim3(B, 10), dim3(256), 0, stream>>>(logits, pm, pl, pgsum, extv, alphasT, out);
}